// Round 7
// baseline (218.646 us; speedup 1.0000x reference)
//
#include <hip/hip_runtime.h>
#include <math.h>

constexpr int kN = 20000;
constexpr int kD = 8;
constexpr int kE = 100000;
constexpr int kM = kN * 9;            // 180000 level-1 rows (== M rows)
constexpr int kTiles1 = kM / 16;      // 11250 M-row tiles
constexpr int kTilesN = kN / 16;      // 1250 node tiles
constexpr float kEps = 1e-5f;

// stats float indices
constexpr int S_SUM1 = 0, S_SQ1 = 128, S_SUM2 = 256, S_SQ2 = 320;

// ws layout (bytes). Peak live ~28 MB.
constexpr size_t OFF_M     = 0;          // bf16 [180000][64] = 23.04 MB
constexpr size_t OFF_PRE2  = 23040000;   // bf16 [20000][64]  = 2.56 MB
constexpr size_t OFF_STATS = 25600000;   // 384 f32
constexpr size_t OFF_CNT   = 25601536;   // f32 [180000]
constexpr size_t OFF_RI    = 26321536;   // i32 [180000]

typedef short short8 __attribute__((ext_vector_type(8)));
typedef float floatx4 __attribute__((ext_vector_type(4)));

__device__ __forceinline__ unsigned f2bf(float f) {  // f32 -> bf16 (RNE)
  unsigned u = __float_as_uint(f);
  u += 0x7fffu + ((u >> 16) & 1u);
  return u >> 16;
}

// ---------------------------------------------------------------------------
// K0: (a) per-node prefix means M[c][r]; (b) rowinfo[m] + cnt multiplicities.
// Also zeroes the scalar output (drops one memset dispatch).
// ---------------------------------------------------------------------------
__global__ __launch_bounds__(256) void k0_prefix(
    const float* __restrict__ x, const float* __restrict__ node_ts,
    const int* __restrict__ nidx, const float* __restrict__ nts,
    unsigned short* __restrict__ M, int* __restrict__ rowinfo,
    float* __restrict__ cntf, float* __restrict__ out)
{
  if (blockIdx.x == 0 && threadIdx.x == 0) *out = 0.f;

  // ---- part 1: prefix means (wave per node) ----
  int c = blockIdx.x * 4 + (threadIdx.x >> 6);
  const int lane = threadIdx.x & 63;
  c = __builtin_amdgcn_readfirstlane(c);

  float ts[8]; int id[8];
#pragma unroll
  for (int j = 0; j < kD; ++j) { ts[j] = nts[c * kD + j]; id[j] = nidx[c * kD + j]; }

#define CSWAP(A, B)                                                   \
  { float ta = ts[A], tb = ts[B]; int ia = id[A], ib = id[B];         \
    bool sw = tb < ta;                                                \
    ts[A] = sw ? tb : ta; ts[B] = sw ? ta : tb;                       \
    id[A] = sw ? ib : ia; id[B] = sw ? ia : ib; }
  CSWAP(0, 1) CSWAP(2, 3) CSWAP(0, 2) CSWAP(1, 3) CSWAP(1, 2)
  CSWAP(4, 5) CSWAP(6, 7) CSWAP(4, 6) CSWAP(5, 7) CSWAP(5, 6)
  CSWAP(0, 4) CSWAP(1, 5) CSWAP(2, 6) CSWAP(3, 7)
  CSWAP(2, 4) CSWAP(3, 5)
  CSWAP(1, 2) CSWAP(3, 4) CSWAP(5, 6)
#undef CSWAP

  float s = x[c * 64 + lane];
  unsigned short* mp = M + (size_t)c * 9 * 64 + lane;
  mp[0] = (unsigned short)f2bf(s);
#pragma unroll
  for (int r = 1; r <= kD; ++r) {
    s += x[id[r - 1] * 64 + lane];
    mp[r * 64] = (unsigned short)f2bf(s / (float)(r + 1));
  }

  // ---- part 2: rowinfo + counts (thread per row) ----
  const int m = blockIdx.x * 256 + threadIdx.x;
  if (m < kM) {
    const int n = (int)((unsigned)m / 9u);
    const int slot = m - n * 9;
    int cc; float t;
    if (slot < kD) { cc = nidx[n * kD + slot]; t = nts[n * kD + slot]; }
    else           { cc = n;                   t = node_ts[n]; }
    int rank = 0;
#pragma unroll
    for (int j = 0; j < kD; ++j) rank += (nts[cc * kD + j] <= t) ? 1 : 0;
    rowinfo[m] = cc * 9 + rank;
    atomicAdd(&cntf[cc * 9 + rank], 1.0f);
  }
}

// ---------------------------------------------------------------------------
// K1: BN1 stats without materializing pre1 (count-weighted streaming GEMM1).
// ---------------------------------------------------------------------------
__global__ __launch_bounds__(256, 3) void k1_stats(
    const unsigned short* __restrict__ M, const float* __restrict__ cntf,
    const float* __restrict__ W1, const float* __restrict__ b1,
    float* __restrict__ stats)
{
  __shared__ unsigned short W1T[128 * 72];   // padded: 2-way bank alias, free
  __shared__ float redS[256][8];
  __shared__ float redQ[256][8];

  const int tid = threadIdx.x;
  const int lane = tid & 63;
  const int wave = tid >> 6;
  const int l15 = lane & 15;
  const int q = lane >> 4;

  for (int i = tid; i < 8192; i += 256) {
    int n = i >> 6, k = i & 63;
    W1T[n * 72 + k] = (unsigned short)f2bf(W1[k * 128 + n]);
  }
  __syncthreads();

  short8 bf[8][2];
#pragma unroll
  for (int cc = 0; cc < 8; ++cc)
#pragma unroll
    for (int s = 0; s < 2; ++s)
      bf[cc][s] = *(const short8*)&W1T[(cc * 16 + l15) * 72 + q * 8 + s * 32];

  float b1c[8];
#pragma unroll
  for (int cc = 0; cc < 8; ++cc) b1c[cc] = b1[cc * 16 + l15];

  float sum8[8], sq8[8];
#pragma unroll
  for (int cc = 0; cc < 8; ++cc) { sum8[cc] = 0.f; sq8[cc] = 0.f; }

  const int gw = blockIdx.x * 4 + wave;
  const int nw = gridDim.x * 4;

  for (int t = gw; t < kTiles1; t += nw) {
    const unsigned short* mp = M + (size_t)(t * 16 + l15) * 64;
    short8 af0 = *(const short8*)(mp + q * 8);
    short8 af1 = *(const short8*)(mp + 32 + q * 8);
    float c4[4];
#pragma unroll
    for (int i = 0; i < 4; ++i) c4[i] = cntf[t * 16 + q * 4 + i];

    floatx4 acc[8];
#pragma unroll
    for (int cc = 0; cc < 8; ++cc) {
      acc[cc] = (floatx4){0.f, 0.f, 0.f, 0.f};
      acc[cc] = __builtin_amdgcn_mfma_f32_16x16x32_bf16(af0, bf[cc][0], acc[cc], 0, 0, 0);
      acc[cc] = __builtin_amdgcn_mfma_f32_16x16x32_bf16(af1, bf[cc][1], acc[cc], 0, 0, 0);
    }
#pragma unroll
    for (int cc = 0; cc < 8; ++cc) {
#pragma unroll
      for (int i = 0; i < 4; ++i) {
        float v = acc[cc][i] + b1c[cc];
        sum8[cc] += c4[i] * v;
        sq8[cc]  += c4[i] * v * v;
      }
    }
  }

  __syncthreads();
#pragma unroll
  for (int cc = 0; cc < 8; ++cc) { redS[tid][cc] = sum8[cc]; redQ[tid][cc] = sq8[cc]; }
  __syncthreads();
  if (tid < 128) {
    int cc = tid >> 4, r15 = tid & 15;
    float s = 0.f, qq = 0.f;
#pragma unroll
    for (int w = 0; w < 4; ++w)
#pragma unroll
      for (int p = 0; p < 4; ++p) {
        int T = w * 64 + p * 16 + r15;
        s += redS[T][cc]; qq += redQ[T][cc];
      }
    atomicAdd(&stats[S_SUM1 + tid], s);
    atomicAdd(&stats[S_SQ1 + tid], qq);
  }
}

// ---------------------------------------------------------------------------
// K3: R5's proven structure (40 µs) + LDS overlay: sm overlays the DEAD
// W1T/W2T staging arrays (fragments live in registers after the prologue).
// LDS 78.8 KB -> 43.0 KB => 3 blocks/CU (12 waves/CU, +50% TLP for the
// random M gathers). (256,2) keeps VGPR <=128: no scratch spills (R6's
// regression: (256,3)=84 VGPR spilled, WRITE_SIZE 7.8->22 MB).
// Grid 625: all co-resident at 3 blocks/CU, exactly 2 tiles/block.
// Body/barriers byte-identical to R5.
// ---------------------------------------------------------------------------
__global__ __launch_bounds__(256, 2) void k3_fused(
    const unsigned short* __restrict__ M, const int* __restrict__ rowinfo,
    const float* __restrict__ node_ts, const float* __restrict__ nts,
    const float* __restrict__ stats_in, const float* __restrict__ g1,
    const float* __restrict__ be1, const float* __restrict__ W1,
    const float* __restrict__ b1, const float* __restrict__ W2,
    const float* __restrict__ b2, float* __restrict__ stats_out,
    unsigned short* __restrict__ pre2)
{
  // staging: [W1T 18432 | W2T 17408] = 35840  (dead after prologue)
  // working: [sm 38016] overlays both; aggT/wlds/winv beyond 38016.
  __shared__ __attribute__((aligned(16))) char lds[43008];
  unsigned short* W1T  = (unsigned short*)lds;             // 128*72
  unsigned short* W2T  = (unsigned short*)(lds + 18432);   // 64*136
  unsigned short* sm   = (unsigned short*)lds;             // 144*132
  unsigned short* aggT = (unsigned short*)(lds + 38016);   // 16*136
  float* wlds = (float*)(lds + 42368);                     // 144
  float* winv = (float*)(lds + 42944);                     // 16

  const int tid = threadIdx.x;
  const int lane = tid & 63;
  const int wave = tid >> 6;
  const int l15 = lane & 15;
  const int q = lane >> 4;

  // ---- issue first tile's rowinfo loads immediately (in flight during
  //      weight staging) ----
  int tb = blockIdx.x;
  int ri0 = rowinfo[tb * 144 + wave * 16 + l15];
  int ri1 = rowinfo[tb * 144 + 64 + wave * 16 + l15];
  int ri2 = 0;
  if (wave == 0) ri2 = rowinfo[tb * 144 + 128 + l15];

  // ---- stage weights ----
  for (int i = tid; i < 8192; i += 256) {
    int nn = i >> 6, k = i & 63;
    W1T[nn * 72 + k] = (unsigned short)f2bf(W1[k * 128 + nn]);
  }
  for (int i = tid; i < 8192; i += 256) {
    int nn = i >> 7, k = i & 127;
    W2T[nn * 136 + k] = (unsigned short)f2bf(W2[k * 64 + nn]);
  }
  __syncthreads();

  // ---- fragments + fused BN1 constants to registers ----
  short8 bf[8][2];
  float scc[8], shc[8];
#pragma unroll
  for (int cc = 0; cc < 8; ++cc) {
    int col = cc * 16 + l15;
#pragma unroll
    for (int s = 0; s < 2; ++s)
      bf[cc][s] = *(const short8*)&W1T[col * 72 + q * 8 + s * 32];
    float mean = stats_in[S_SUM1 + col] * (1.f / kM);
    float var  = stats_in[S_SQ1 + col] * (1.f / kM) - mean * mean;
    float sg   = g1[col] * rsqrtf(var + kEps);
    scc[cc] = sg;
    shc[cc] = (b1[col] - mean) * sg + be1[col];   // b1 folded into shift
  }
  short8 bfr2[4];
#pragma unroll
  for (int s = 0; s < 4; ++s)
    bfr2[s] = *(const short8*)&W2T[(wave * 16 + l15) * 136 + q * 8 + s * 32];
  const float b2w = b2[wave * 16 + l15];
  __syncthreads();   // all W1T/W2T reads complete before sm overlays them

  float sumS = 0.f, sumQ = 0.f;   // BN2 partials, col = wave*16+l15

  for (; tb < kTilesN; tb += gridDim.x) {
    const int node0 = tb * 16;

    // ---- issue ALL of this tile's M gathers up-front (independent) ----
    const unsigned short* mp0 = M + (size_t)ri0 * 64;
    const unsigned short* mp1 = M + (size_t)ri1 * 64;
    short8 a00 = *(const short8*)(mp0 + q * 8);
    short8 a01 = *(const short8*)(mp0 + 32 + q * 8);
    short8 a10 = *(const short8*)(mp1 + q * 8);
    short8 a11 = *(const short8*)(mp1 + 32 + q * 8);
    short8 a20{}, a21{};
    if (wave == 0) {
      const unsigned short* mp2 = M + (size_t)ri2 * 64;
      a20 = *(const short8*)(mp2 + q * 8);
      a21 = *(const short8*)(mp2 + 32 + q * 8);
    }

    // ---- prefetch NEXT tile's rowinfo (hidden under this tile's work) ----
    {
      int ntb = tb + gridDim.x;
      if (ntb < kTilesN) {
        ri0 = rowinfo[ntb * 144 + wave * 16 + l15];
        ri1 = rowinfo[ntb * 144 + 64 + wave * 16 + l15];
        if (wave == 0) ri2 = rowinfo[ntb * 144 + 128 + l15];
      }
    }

    // ---- mask weights ----
    if (tid < 144) {
      int ln = tid / 9;
      int slot = tid - ln * 9;
      int nn = node0 + ln;
      float w = 1.f;
      if (slot < kD) w = (nts[nn * kD + slot] <= node_ts[nn]) ? 1.f : 0.f;
      wlds[tid] = w;
    }
    __syncthreads();    // B1: wlds ready, sm reuse ordered, gathers drained
    if (tid < 16) {
      float swv = 0.f;
#pragma unroll
      for (int r = 0; r < 9; ++r) swv += wlds[tid * 9 + r];
      winv[tid] = 1.f / swv;
    }

    // ---- ph3: GEMM1 + BN1 + ReLU + mask-weight -> sm (bf16) ----
#define ROWTILE(TL, A0, A1)                                                  \
    {                                                                        \
      floatx4 acc[8];                                                        \
      _Pragma("unroll")                                                      \
      for (int cc = 0; cc < 8; ++cc) {                                       \
        acc[cc] = (floatx4){0.f, 0.f, 0.f, 0.f};                             \
        acc[cc] = __builtin_amdgcn_mfma_f32_16x16x32_bf16(A0, bf[cc][0], acc[cc], 0, 0, 0); \
        acc[cc] = __builtin_amdgcn_mfma_f32_16x16x32_bf16(A1, bf[cc][1], acc[cc], 0, 0, 0); \
      }                                                                      \
      float w4[4];                                                           \
      _Pragma("unroll")                                                      \
      for (int i = 0; i < 4; ++i) w4[i] = wlds[(TL) * 16 + q * 4 + i];       \
      _Pragma("unroll")                                                      \
      for (int cc = 0; cc < 8; ++cc) {                                       \
        int col = cc * 16 + l15;                                             \
        _Pragma("unroll")                                                    \
        for (int i = 0; i < 4; ++i) {                                        \
          float val = fmaxf(fmaf(acc[cc][i], scc[cc], shc[cc]), 0.f) * w4[i];\
          sm[((TL) * 16 + q * 4 + i) * 132 + col] = (unsigned short)f2bf(val);\
        }                                                                    \
      }                                                                      \
    }
    ROWTILE(wave, a00, a01)
    ROWTILE(wave + 4, a10, a11)
    if (wave == 0) ROWTILE(8, a20, a21)
#undef ROWTILE
    __syncthreads();                               // B2: sm + winv ready

    // ---- ph5: 9-slot reduce -> aggT ----
#pragma unroll
    for (int k = 0; k < 4; ++k) {
      int it = tid + k * 256;        // (node, colpair)
      int nd = it >> 6, cp = it & 63;
      float s0 = 0.f, s1 = 0.f;
#pragma unroll
      for (int r = 0; r < 9; ++r) {
        unsigned u = *(const unsigned*)&sm[(nd * 9 + r) * 132 + cp * 2];
        s0 += __uint_as_float(u << 16);
        s1 += __uint_as_float(u & 0xffff0000u);
      }
      float iv = winv[nd];
      *(unsigned*)&aggT[nd * 136 + cp * 2] = f2bf(s0 * iv) | (f2bf(s1 * iv) << 16);
    }
    __syncthreads();                               // B3: aggT ready

    // ---- ph7: GEMM2 -> pre2 (bf16) + BN2 partials ----
    short8 af2[4];
#pragma unroll
    for (int s = 0; s < 4; ++s)
      af2[s] = *(const short8*)&aggT[l15 * 136 + q * 8 + s * 32];
    floatx4 acc2 = (floatx4){0.f, 0.f, 0.f, 0.f};
#pragma unroll
    for (int s = 0; s < 4; ++s)
      acc2 = __builtin_amdgcn_mfma_f32_16x16x32_bf16(af2[s], bfr2[s], acc2, 0, 0, 0);
#pragma unroll
    for (int i = 0; i < 4; ++i) {
      float v = acc2[i] + b2w;
      int nrow = node0 + q * 4 + i;
      pre2[(size_t)nrow * 64 + wave * 16 + l15] = (unsigned short)f2bf(v);
      sumS += v; sumQ += v * v;
    }
    // loop-carried LDS reuse is ordered by next iteration's B1.
  }

  sumS += __shfl_xor(sumS, 16); sumS += __shfl_xor(sumS, 32);
  sumQ += __shfl_xor(sumQ, 16); sumQ += __shfl_xor(sumQ, 32);
  if (lane < 16) {
    atomicAdd(&stats_out[S_SUM2 + wave * 16 + lane], sumS);
    atomicAdd(&stats_out[S_SQ2 + wave * 16 + lane], sumQ);
  }
}

// ---------------------------------------------------------------------------
// K6: loss with BN2+ReLU+Wd applied inline on gathered bf16 pre2 rows
// (working set 2.56 MB -> XCD-L2-resident; 128 B per gathered row).
// ---------------------------------------------------------------------------
__global__ __launch_bounds__(256) void k6_loss(
    const unsigned short* __restrict__ pre2, const float* __restrict__ stats,
    const float* __restrict__ g2, const float* __restrict__ be2,
    const float* __restrict__ Wd, const int* __restrict__ tgt,
    const int* __restrict__ neg, const float* __restrict__ bd,
    float* __restrict__ out)
{
  __shared__ float scl[64], shl[64], wdl[64];
  __shared__ float redl[256];
  const int tid = threadIdx.x;
  if (tid < 64) {
    float mean = stats[S_SUM2 + tid] * (1.f / kN);
    float var  = stats[S_SQ2 + tid] * (1.f / kN) - mean * mean;
    float s    = g2[tid] * rsqrtf(var + kEps);
    scl[tid] = s; shl[tid] = be2[tid] - mean * s; wdl[tid] = Wd[tid];
  }
  __syncthreads();

  const int tq = tid & 15;
  const int qb = tid >> 4;
  const int c0 = tq * 4;
  const float4 sc4 = {scl[c0], scl[c0 + 1], scl[c0 + 2], scl[c0 + 3]};
  const float4 sh4 = {shl[c0], shl[c0 + 1], shl[c0 + 2], shl[c0 + 3]};
  const float4 wd4 = {wdl[c0], wdl[c0 + 1], wdl[c0 + 2], wdl[c0 + 3]};
  const float bd0 = bd[0];

  float lsum = 0.f;
  const int e0 = blockIdx.x * 128 + qb * 8;
#pragma unroll
  for (int it = 0; it < 8; ++it) {
    int e = e0 + it;
    if (e < 2 * kE) {
      int i, j; float lab;
      if (e < kE) { i = tgt[e];      j = tgt[kE + e]; lab = 1.f; }
      else        { i = neg[e - kE]; j = neg[e];      lab = 0.f; }
      uint2 ua = *(const uint2*)&pre2[(size_t)i * 64 + c0];
      uint2 ub = *(const uint2*)&pre2[(size_t)j * 64 + c0];
      float a0 = __uint_as_float(ua.x << 16), a1 = __uint_as_float(ua.x & 0xffff0000u);
      float a2 = __uint_as_float(ua.y << 16), a3 = __uint_as_float(ua.y & 0xffff0000u);
      float b0 = __uint_as_float(ub.x << 16), b1v = __uint_as_float(ub.x & 0xffff0000u);
      float b2v = __uint_as_float(ub.y << 16), b3 = __uint_as_float(ub.y & 0xffff0000u);
      float ei0 = fmaxf(fmaf(a0, sc4.x, sh4.x), 0.f) * wd4.x;
      float ei1 = fmaxf(fmaf(a1, sc4.y, sh4.y), 0.f) * wd4.y;
      float ei2 = fmaxf(fmaf(a2, sc4.z, sh4.z), 0.f) * wd4.z;
      float ei3 = fmaxf(fmaf(a3, sc4.w, sh4.w), 0.f) * wd4.w;
      float ej0 = fmaxf(fmaf(b0, sc4.x, sh4.x), 0.f);
      float ej1 = fmaxf(fmaf(b1v, sc4.y, sh4.y), 0.f);
      float ej2 = fmaxf(fmaf(b2v, sc4.z, sh4.z), 0.f);
      float ej3 = fmaxf(fmaf(b3, sc4.w, sh4.w), 0.f);
      float p = ei0 * ej0 + ei1 * ej1 + ei2 * ej2 + ei3 * ej3;
      p += __shfl_xor(p, 1); p += __shfl_xor(p, 2);
      p += __shfl_xor(p, 4); p += __shfl_xor(p, 8);
      p += bd0;
      float l = fmaxf(p, 0.f) - p * lab + log1pf(expf(-fabsf(p)));
      if (tq == 0) lsum += l;
    }
  }
  redl[tid] = lsum;
  __syncthreads();
  for (int s = 128; s > 0; s >>= 1) {
    if (tid < s) redl[tid] += redl[tid + s];
    __syncthreads();
  }
  if (tid == 0) atomicAdd(out, redl[0] * (1.f / (2 * kE)));
}

extern "C" void kernel_launch(void* const* d_in, const int* in_sizes, int n_in,
                              void* d_out, int out_size, void* d_ws, size_t ws_size,
                              hipStream_t stream) {
  (void)in_sizes; (void)n_in; (void)out_size; (void)ws_size;
  const float* x       = (const float*)d_in[0];
  const float* node_ts = (const float*)d_in[1];
  const int*   nidx    = (const int*)d_in[2];
  const float* nts     = (const float*)d_in[3];
  const int*   tgt     = (const int*)d_in[4];
  const int*   neg     = (const int*)d_in[5];
  const float* W1      = (const float*)d_in[6];
  const float* b1      = (const float*)d_in[7];
  const float* g1      = (const float*)d_in[8];
  const float* be1     = (const float*)d_in[9];
  const float* W2      = (const float*)d_in[10];
  const float* b2      = (const float*)d_in[11];
  const float* g2      = (const float*)d_in[12];
  const float* be2     = (const float*)d_in[13];
  const float* Wd      = (const float*)d_in[14];
  const float* bd      = (const float*)d_in[15];

  char* ws = (char*)d_ws;
  unsigned short* Mbuf = (unsigned short*)(ws + OFF_M);
  unsigned short* pre2 = (unsigned short*)(ws + OFF_PRE2);
  float* stats = (float*)(ws + OFF_STATS);
  float* cntf  = (float*)(ws + OFF_CNT);
  int*   rinfo = (int*)(ws + OFF_RI);
  float* out   = (float*)d_out;

  // zero stats + cnt in one contiguous memset (out zeroed in k0)
  hipMemsetAsync(ws + OFF_STATS, 0, 1536 + 720000, stream);

  k0_prefix<<<kN / 4, 256, 0, stream>>>(x, node_ts, nidx, nts, Mbuf, rinfo,
                                        cntf, out);
  k1_stats<<<704, 256, 0, stream>>>(Mbuf, cntf, W1, b1, stats);
  k3_fused<<<625, 256, 0, stream>>>(Mbuf, rinfo, node_ts, nts, stats, g1, be1,
                                    W1, b1, W2, b2, stats, pre2);
  k6_loss<<<(2 * kE + 127) / 128, 256, 0, stream>>>(pre2, stats, g2, be2, Wd,
                                                    tgt, neg, bd, out);
}

// Round 8
// 199.570 us; speedup vs baseline: 1.0956x; 1.0956x over previous
//
#include <hip/hip_runtime.h>
#include <math.h>

constexpr int kN = 20000;
constexpr int kD = 8;
constexpr int kE = 100000;
constexpr int kM = kN * 9;            // 180000 level-1 rows (== M rows)
constexpr int kTiles1 = kM / 16;      // 11250 M-row tiles
constexpr int kTilesN = kN / 16;      // 1250 node tiles
constexpr float kEps = 1e-5f;

// stats float indices
constexpr int S_SUM1 = 0, S_SQ1 = 128, S_SUM2 = 256, S_SQ2 = 320;

// ws layout (bytes). Peak live ~28 MB.
constexpr size_t OFF_M     = 0;          // bf16 [180000][64] = 23.04 MB
constexpr size_t OFF_PRE2  = 23040000;   // bf16 [20000][64]  = 2.56 MB
constexpr size_t OFF_STATS = 25600000;   // 384 f32
constexpr size_t OFF_CNT   = 25601536;   // f32 [180000]
constexpr size_t OFF_RI    = 26321536;   // i32 [180000]

typedef short short8 __attribute__((ext_vector_type(8)));
typedef float floatx4 __attribute__((ext_vector_type(4)));

__device__ __forceinline__ unsigned f2bf(float f) {  // f32 -> bf16 (RNE)
  unsigned u = __float_as_uint(f);
  u += 0x7fffu + ((u >> 16) & 1u);
  return u >> 16;
}

// ---------------------------------------------------------------------------
// K0: (a) per-node prefix means M[c][r]; (b) rowinfo[m] + cnt multiplicities.
// Neighbor ts/idx rows (32B, aligned) loaded as float4/int4 pairs instead of
// 8 scalar dwords (4x fewer VMEM instructions on the uncoalesced gathers).
// Also zeroes the scalar output (drops one memset dispatch).
// ---------------------------------------------------------------------------
__global__ __launch_bounds__(256) void k0_prefix(
    const float* __restrict__ x, const float* __restrict__ node_ts,
    const int* __restrict__ nidx, const float* __restrict__ nts,
    unsigned short* __restrict__ M, int* __restrict__ rowinfo,
    float* __restrict__ cntf, float* __restrict__ out)
{
  if (blockIdx.x == 0 && threadIdx.x == 0) *out = 0.f;

  // ---- part 1: prefix means (wave per node) ----
  int c = blockIdx.x * 4 + (threadIdx.x >> 6);
  const int lane = threadIdx.x & 63;
  c = __builtin_amdgcn_readfirstlane(c);

  float4 t0 = *(const float4*)&nts[c * kD];
  float4 t1 = *(const float4*)&nts[c * kD + 4];
  int4   i0 = *(const int4*)&nidx[c * kD];
  int4   i1 = *(const int4*)&nidx[c * kD + 4];
  float ts[8] = {t0.x, t0.y, t0.z, t0.w, t1.x, t1.y, t1.z, t1.w};
  int   id[8] = {i0.x, i0.y, i0.z, i0.w, i1.x, i1.y, i1.z, i1.w};

#define CSWAP(A, B)                                                   \
  { float ta = ts[A], tb = ts[B]; int ia = id[A], ib = id[B];         \
    bool sw = tb < ta;                                                \
    ts[A] = sw ? tb : ta; ts[B] = sw ? ta : tb;                       \
    id[A] = sw ? ib : ia; id[B] = sw ? ia : ib; }
  CSWAP(0, 1) CSWAP(2, 3) CSWAP(0, 2) CSWAP(1, 3) CSWAP(1, 2)
  CSWAP(4, 5) CSWAP(6, 7) CSWAP(4, 6) CSWAP(5, 7) CSWAP(5, 6)
  CSWAP(0, 4) CSWAP(1, 5) CSWAP(2, 6) CSWAP(3, 7)
  CSWAP(2, 4) CSWAP(3, 5)
  CSWAP(1, 2) CSWAP(3, 4) CSWAP(5, 6)
#undef CSWAP

  float s = x[c * 64 + lane];
  unsigned short* mp = M + (size_t)c * 9 * 64 + lane;
  mp[0] = (unsigned short)f2bf(s);
#pragma unroll
  for (int r = 1; r <= kD; ++r) {
    s += x[id[r - 1] * 64 + lane];
    mp[r * 64] = (unsigned short)f2bf(s / (float)(r + 1));
  }

  // ---- part 2: rowinfo + counts (thread per row) ----
  const int m = blockIdx.x * 256 + threadIdx.x;
  if (m < kM) {
    const int n = (int)((unsigned)m / 9u);
    const int slot = m - n * 9;
    int cc; float t;
    if (slot < kD) { cc = nidx[n * kD + slot]; t = nts[n * kD + slot]; }
    else           { cc = n;                   t = node_ts[n]; }
    float4 a = *(const float4*)&nts[cc * kD];
    float4 b = *(const float4*)&nts[cc * kD + 4];
    int rank = (a.x <= t) + (a.y <= t) + (a.z <= t) + (a.w <= t)
             + (b.x <= t) + (b.y <= t) + (b.z <= t) + (b.w <= t);
    rowinfo[m] = cc * 9 + rank;
    atomicAdd(&cntf[cc * 9 + rank], 1.0f);
  }
}

// ---------------------------------------------------------------------------
// K1: BN1 stats without materializing pre1 (count-weighted streaming GEMM1).
// ---------------------------------------------------------------------------
__global__ __launch_bounds__(256, 3) void k1_stats(
    const unsigned short* __restrict__ M, const float* __restrict__ cntf,
    const float* __restrict__ W1, const float* __restrict__ b1,
    float* __restrict__ stats)
{
  __shared__ unsigned short W1T[128 * 72];   // padded: 2-way bank alias, free
  __shared__ float redS[256][8];
  __shared__ float redQ[256][8];

  const int tid = threadIdx.x;
  const int lane = tid & 63;
  const int wave = tid >> 6;
  const int l15 = lane & 15;
  const int q = lane >> 4;

  for (int i = tid; i < 8192; i += 256) {
    int n = i >> 6, k = i & 63;
    W1T[n * 72 + k] = (unsigned short)f2bf(W1[k * 128 + n]);
  }
  __syncthreads();

  short8 bf[8][2];
#pragma unroll
  for (int cc = 0; cc < 8; ++cc)
#pragma unroll
    for (int s = 0; s < 2; ++s)
      bf[cc][s] = *(const short8*)&W1T[(cc * 16 + l15) * 72 + q * 8 + s * 32];

  float b1c[8];
#pragma unroll
  for (int cc = 0; cc < 8; ++cc) b1c[cc] = b1[cc * 16 + l15];

  float sum8[8], sq8[8];
#pragma unroll
  for (int cc = 0; cc < 8; ++cc) { sum8[cc] = 0.f; sq8[cc] = 0.f; }

  const int gw = blockIdx.x * 4 + wave;
  const int nw = gridDim.x * 4;

  for (int t = gw; t < kTiles1; t += nw) {
    const unsigned short* mp = M + (size_t)(t * 16 + l15) * 64;
    short8 af0 = *(const short8*)(mp + q * 8);
    short8 af1 = *(const short8*)(mp + 32 + q * 8);
    float c4[4];
#pragma unroll
    for (int i = 0; i < 4; ++i) c4[i] = cntf[t * 16 + q * 4 + i];

    floatx4 acc[8];
#pragma unroll
    for (int cc = 0; cc < 8; ++cc) {
      acc[cc] = (floatx4){0.f, 0.f, 0.f, 0.f};
      acc[cc] = __builtin_amdgcn_mfma_f32_16x16x32_bf16(af0, bf[cc][0], acc[cc], 0, 0, 0);
      acc[cc] = __builtin_amdgcn_mfma_f32_16x16x32_bf16(af1, bf[cc][1], acc[cc], 0, 0, 0);
    }
#pragma unroll
    for (int cc = 0; cc < 8; ++cc) {
#pragma unroll
      for (int i = 0; i < 4; ++i) {
        float v = acc[cc][i] + b1c[cc];
        sum8[cc] += c4[i] * v;
        sq8[cc]  += c4[i] * v * v;
      }
    }
  }

  __syncthreads();
#pragma unroll
  for (int cc = 0; cc < 8; ++cc) { redS[tid][cc] = sum8[cc]; redQ[tid][cc] = sq8[cc]; }
  __syncthreads();
  if (tid < 128) {
    int cc = tid >> 4, r15 = tid & 15;
    float s = 0.f, qq = 0.f;
#pragma unroll
    for (int w = 0; w < 4; ++w)
#pragma unroll
      for (int p = 0; p < 4; ++p) {
        int T = w * 64 + p * 16 + r15;
        s += redS[T][cc]; qq += redQ[T][cc];
      }
    atomicAdd(&stats[S_SUM1 + tid], s);
    atomicAdd(&stats[S_SQ1 + tid], qq);
  }
}

// ---------------------------------------------------------------------------
// K3: byte-identical to R5's proven config (the ONLY one measured <=42 µs):
// separate persistent W1T/W2T LDS (78.8 KB), (256,2), grid 512 => exactly
// 2 blocks/CU, single scheduling round, no tail. Grid-625/overlay variants
// (R4/R6/R7) all regressed to 52-55 µs via scheduling tail or spills.
// ---------------------------------------------------------------------------
__global__ __launch_bounds__(256, 2) void k3_fused(
    const unsigned short* __restrict__ M, const int* __restrict__ rowinfo,
    const float* __restrict__ node_ts, const float* __restrict__ nts,
    const float* __restrict__ stats_in, const float* __restrict__ g1,
    const float* __restrict__ be1, const float* __restrict__ W1,
    const float* __restrict__ b1, const float* __restrict__ W2,
    const float* __restrict__ b2, float* __restrict__ stats_out,
    unsigned short* __restrict__ pre2)
{
  __shared__ __attribute__((aligned(16))) unsigned short W1T[128 * 72];
  __shared__ __attribute__((aligned(16))) unsigned short W2T[64 * 136];
  __shared__ __attribute__((aligned(16))) unsigned short sm[144 * 132];
  __shared__ __attribute__((aligned(16))) unsigned short aggT[16 * 136];
  __shared__ float wlds[144];
  __shared__ float winv[16];

  const int tid = threadIdx.x;
  const int lane = tid & 63;
  const int wave = tid >> 6;
  const int l15 = lane & 15;
  const int q = lane >> 4;

  // ---- issue first tile's rowinfo loads immediately (in flight during
  //      weight staging) ----
  int tb = blockIdx.x;
  int ri0 = rowinfo[tb * 144 + wave * 16 + l15];
  int ri1 = rowinfo[tb * 144 + 64 + wave * 16 + l15];
  int ri2 = 0;
  if (wave == 0) ri2 = rowinfo[tb * 144 + 128 + l15];

  // ---- stage weights (persistent LDS; fragments re-readable) ----
  for (int i = tid; i < 8192; i += 256) {
    int nn = i >> 6, k = i & 63;
    W1T[nn * 72 + k] = (unsigned short)f2bf(W1[k * 128 + nn]);
  }
  for (int i = tid; i < 8192; i += 256) {
    int nn = i >> 7, k = i & 127;
    W2T[nn * 136 + k] = (unsigned short)f2bf(W2[k * 64 + nn]);
  }
  __syncthreads();

  // ---- fragments + fused BN1 constants to registers ----
  short8 bf[8][2];
  float scc[8], shc[8];
#pragma unroll
  for (int cc = 0; cc < 8; ++cc) {
    int col = cc * 16 + l15;
#pragma unroll
    for (int s = 0; s < 2; ++s)
      bf[cc][s] = *(const short8*)&W1T[col * 72 + q * 8 + s * 32];
    float mean = stats_in[S_SUM1 + col] * (1.f / kM);
    float var  = stats_in[S_SQ1 + col] * (1.f / kM) - mean * mean;
    float sg   = g1[col] * rsqrtf(var + kEps);
    scc[cc] = sg;
    shc[cc] = (b1[col] - mean) * sg + be1[col];   // b1 folded into shift
  }
  short8 bfr2[4];
#pragma unroll
  for (int s = 0; s < 4; ++s)
    bfr2[s] = *(const short8*)&W2T[(wave * 16 + l15) * 136 + q * 8 + s * 32];
  const float b2w = b2[wave * 16 + l15];

  float sumS = 0.f, sumQ = 0.f;   // BN2 partials, col = wave*16+l15

  for (; tb < kTilesN; tb += gridDim.x) {
    const int node0 = tb * 16;

    // ---- issue ALL of this tile's M gathers up-front (independent) ----
    const unsigned short* mp0 = M + (size_t)ri0 * 64;
    const unsigned short* mp1 = M + (size_t)ri1 * 64;
    short8 a00 = *(const short8*)(mp0 + q * 8);
    short8 a01 = *(const short8*)(mp0 + 32 + q * 8);
    short8 a10 = *(const short8*)(mp1 + q * 8);
    short8 a11 = *(const short8*)(mp1 + 32 + q * 8);
    short8 a20{}, a21{};
    if (wave == 0) {
      const unsigned short* mp2 = M + (size_t)ri2 * 64;
      a20 = *(const short8*)(mp2 + q * 8);
      a21 = *(const short8*)(mp2 + 32 + q * 8);
    }

    // ---- prefetch NEXT tile's rowinfo (hidden under this tile's work) ----
    {
      int ntb = tb + gridDim.x;
      if (ntb < kTilesN) {
        ri0 = rowinfo[ntb * 144 + wave * 16 + l15];
        ri1 = rowinfo[ntb * 144 + 64 + wave * 16 + l15];
        if (wave == 0) ri2 = rowinfo[ntb * 144 + 128 + l15];
      }
    }

    // ---- mask weights ----
    if (tid < 144) {
      int ln = tid / 9;
      int slot = tid - ln * 9;
      int nn = node0 + ln;
      float w = 1.f;
      if (slot < kD) w = (nts[nn * kD + slot] <= node_ts[nn]) ? 1.f : 0.f;
      wlds[tid] = w;
    }
    __syncthreads();    // B1: wlds ready, sm reuse ordered, gathers drained
    if (tid < 16) {
      float swv = 0.f;
#pragma unroll
      for (int r = 0; r < 9; ++r) swv += wlds[tid * 9 + r];
      winv[tid] = 1.f / swv;
    }

    // ---- ph3: GEMM1 + BN1 + ReLU + mask-weight -> sm (bf16) ----
#define ROWTILE(TL, A0, A1)                                                  \
    {                                                                        \
      floatx4 acc[8];                                                        \
      _Pragma("unroll")                                                      \
      for (int cc = 0; cc < 8; ++cc) {                                       \
        acc[cc] = (floatx4){0.f, 0.f, 0.f, 0.f};                             \
        acc[cc] = __builtin_amdgcn_mfma_f32_16x16x32_bf16(A0, bf[cc][0], acc[cc], 0, 0, 0); \
        acc[cc] = __builtin_amdgcn_mfma_f32_16x16x32_bf16(A1, bf[cc][1], acc[cc], 0, 0, 0); \
      }                                                                      \
      float w4[4];                                                           \
      _Pragma("unroll")                                                      \
      for (int i = 0; i < 4; ++i) w4[i] = wlds[(TL) * 16 + q * 4 + i];       \
      _Pragma("unroll")                                                      \
      for (int cc = 0; cc < 8; ++cc) {                                       \
        int col = cc * 16 + l15;                                             \
        _Pragma("unroll")                                                    \
        for (int i = 0; i < 4; ++i) {                                        \
          float val = fmaxf(fmaf(acc[cc][i], scc[cc], shc[cc]), 0.f) * w4[i];\
          sm[((TL) * 16 + q * 4 + i) * 132 + col] = (unsigned short)f2bf(val);\
        }                                                                    \
      }                                                                      \
    }
    ROWTILE(wave, a00, a01)
    ROWTILE(wave + 4, a10, a11)
    if (wave == 0) ROWTILE(8, a20, a21)
#undef ROWTILE
    __syncthreads();                               // B2: sm + winv ready

    // ---- ph5: 9-slot reduce -> aggT ----
#pragma unroll
    for (int k = 0; k < 4; ++k) {
      int it = tid + k * 256;        // (node, colpair)
      int nd = it >> 6, cp = it & 63;
      float s0 = 0.f, s1 = 0.f;
#pragma unroll
      for (int r = 0; r < 9; ++r) {
        unsigned u = *(const unsigned*)&sm[(nd * 9 + r) * 132 + cp * 2];
        s0 += __uint_as_float(u << 16);
        s1 += __uint_as_float(u & 0xffff0000u);
      }
      float iv = winv[nd];
      *(unsigned*)&aggT[nd * 136 + cp * 2] = f2bf(s0 * iv) | (f2bf(s1 * iv) << 16);
    }
    __syncthreads();                               // B3: aggT ready

    // ---- ph7: GEMM2 -> pre2 (bf16) + BN2 partials ----
    short8 af2[4];
#pragma unroll
    for (int s = 0; s < 4; ++s)
      af2[s] = *(const short8*)&aggT[l15 * 136 + q * 8 + s * 32];
    floatx4 acc2 = (floatx4){0.f, 0.f, 0.f, 0.f};
#pragma unroll
    for (int s = 0; s < 4; ++s)
      acc2 = __builtin_amdgcn_mfma_f32_16x16x32_bf16(af2[s], bfr2[s], acc2, 0, 0, 0);
#pragma unroll
    for (int i = 0; i < 4; ++i) {
      float v = acc2[i] + b2w;
      int nrow = node0 + q * 4 + i;
      pre2[(size_t)nrow * 64 + wave * 16 + l15] = (unsigned short)f2bf(v);
      sumS += v; sumQ += v * v;
    }
    // loop-carried LDS reuse is ordered by next iteration's B1.
  }

  sumS += __shfl_xor(sumS, 16); sumS += __shfl_xor(sumS, 32);
  sumQ += __shfl_xor(sumQ, 16); sumQ += __shfl_xor(sumQ, 32);
  if (lane < 16) {
    atomicAdd(&stats_out[S_SUM2 + wave * 16 + lane], sumS);
    atomicAdd(&stats_out[S_SQ2 + wave * 16 + lane], sumQ);
  }
}

// ---------------------------------------------------------------------------
// K6: loss with BN2+ReLU+Wd applied inline on gathered bf16 pre2 rows
// (working set 2.56 MB -> XCD-L2-resident; 128 B per gathered row).
// ---------------------------------------------------------------------------
__global__ __launch_bounds__(256) void k6_loss(
    const unsigned short* __restrict__ pre2, const float* __restrict__ stats,
    const float* __restrict__ g2, const float* __restrict__ be2,
    const float* __restrict__ Wd, const int* __restrict__ tgt,
    const int* __restrict__ neg, const float* __restrict__ bd,
    float* __restrict__ out)
{
  __shared__ float scl[64], shl[64], wdl[64];
  __shared__ float redl[256];
  const int tid = threadIdx.x;
  if (tid < 64) {
    float mean = stats[S_SUM2 + tid] * (1.f / kN);
    float var  = stats[S_SQ2 + tid] * (1.f / kN) - mean * mean;
    float s    = g2[tid] * rsqrtf(var + kEps);
    scl[tid] = s; shl[tid] = be2[tid] - mean * s; wdl[tid] = Wd[tid];
  }
  __syncthreads();

  const int tq = tid & 15;
  const int qb = tid >> 4;
  const int c0 = tq * 4;
  const float4 sc4 = {scl[c0], scl[c0 + 1], scl[c0 + 2], scl[c0 + 3]};
  const float4 sh4 = {shl[c0], shl[c0 + 1], shl[c0 + 2], shl[c0 + 3]};
  const float4 wd4 = {wdl[c0], wdl[c0 + 1], wdl[c0 + 2], wdl[c0 + 3]};
  const float bd0 = bd[0];

  float lsum = 0.f;
  const int e0 = blockIdx.x * 128 + qb * 8;
#pragma unroll
  for (int it = 0; it < 8; ++it) {
    int e = e0 + it;
    if (e < 2 * kE) {
      int i, j; float lab;
      if (e < kE) { i = tgt[e];      j = tgt[kE + e]; lab = 1.f; }
      else        { i = neg[e - kE]; j = neg[e];      lab = 0.f; }
      uint2 ua = *(const uint2*)&pre2[(size_t)i * 64 + c0];
      uint2 ub = *(const uint2*)&pre2[(size_t)j * 64 + c0];
      float a0 = __uint_as_float(ua.x << 16), a1 = __uint_as_float(ua.x & 0xffff0000u);
      float a2 = __uint_as_float(ua.y << 16), a3 = __uint_as_float(ua.y & 0xffff0000u);
      float b0 = __uint_as_float(ub.x << 16), b1v = __uint_as_float(ub.x & 0xffff0000u);
      float b2v = __uint_as_float(ub.y << 16), b3 = __uint_as_float(ub.y & 0xffff0000u);
      float ei0 = fmaxf(fmaf(a0, sc4.x, sh4.x), 0.f) * wd4.x;
      float ei1 = fmaxf(fmaf(a1, sc4.y, sh4.y), 0.f) * wd4.y;
      float ei2 = fmaxf(fmaf(a2, sc4.z, sh4.z), 0.f) * wd4.z;
      float ei3 = fmaxf(fmaf(a3, sc4.w, sh4.w), 0.f) * wd4.w;
      float ej0 = fmaxf(fmaf(b0, sc4.x, sh4.x), 0.f);
      float ej1 = fmaxf(fmaf(b1v, sc4.y, sh4.y), 0.f);
      float ej2 = fmaxf(fmaf(b2v, sc4.z, sh4.z), 0.f);
      float ej3 = fmaxf(fmaf(b3, sc4.w, sh4.w), 0.f);
      float p = ei0 * ej0 + ei1 * ej1 + ei2 * ej2 + ei3 * ej3;
      p += __shfl_xor(p, 1); p += __shfl_xor(p, 2);
      p += __shfl_xor(p, 4); p += __shfl_xor(p, 8);
      p += bd0;
      float l = fmaxf(p, 0.f) - p * lab + log1pf(expf(-fabsf(p)));
      if (tq == 0) lsum += l;
    }
  }
  redl[tid] = lsum;
  __syncthreads();
  for (int s = 128; s > 0; s >>= 1) {
    if (tid < s) redl[tid] += redl[tid + s];
    __syncthreads();
  }
  if (tid == 0) atomicAdd(out, redl[0] * (1.f / (2 * kE)));
}

extern "C" void kernel_launch(void* const* d_in, const int* in_sizes, int n_in,
                              void* d_out, int out_size, void* d_ws, size_t ws_size,
                              hipStream_t stream) {
  (void)in_sizes; (void)n_in; (void)out_size; (void)ws_size;
  const float* x       = (const float*)d_in[0];
  const float* node_ts = (const float*)d_in[1];
  const int*   nidx    = (const int*)d_in[2];
  const float* nts     = (const float*)d_in[3];
  const int*   tgt     = (const int*)d_in[4];
  const int*   neg     = (const int*)d_in[5];
  const float* W1      = (const float*)d_in[6];
  const float* b1      = (const float*)d_in[7];
  const float* g1      = (const float*)d_in[8];
  const float* be1     = (const float*)d_in[9];
  const float* W2      = (const float*)d_in[10];
  const float* b2      = (const float*)d_in[11];
  const float* g2      = (const float*)d_in[12];
  const float* be2     = (const float*)d_in[13];
  const float* Wd      = (const float*)d_in[14];
  const float* bd      = (const float*)d_in[15];

  char* ws = (char*)d_ws;
  unsigned short* Mbuf = (unsigned short*)(ws + OFF_M);
  unsigned short* pre2 = (unsigned short*)(ws + OFF_PRE2);
  float* stats = (float*)(ws + OFF_STATS);
  float* cntf  = (float*)(ws + OFF_CNT);
  int*   rinfo = (int*)(ws + OFF_RI);
  float* out   = (float*)d_out;

  // zero stats + cnt in one contiguous memset (out zeroed in k0)
  hipMemsetAsync(ws + OFF_STATS, 0, 1536 + 720000, stream);

  k0_prefix<<<kN / 4, 256, 0, stream>>>(x, node_ts, nidx, nts, Mbuf, rinfo,
                                        cntf, out);
  k1_stats<<<704, 256, 0, stream>>>(Mbuf, cntf, W1, b1, stats);
  k3_fused<<<512, 256, 0, stream>>>(Mbuf, rinfo, node_ts, nts, stats, g1, be1,
                                    W1, b1, W2, b2, stats, pre2);
  k6_loss<<<(2 * kE + 127) / 128, 256, 0, stream>>>(pre2, stats, g2, be2, Wd,
                                                    tgt, neg, bd, out);
}